// Round 1
// baseline (1002.165 us; speedup 1.0000x reference)
//
#include <hip/hip_runtime.h>

#define BB 2048
#define SS 200
#define VV 50257
#define EE 60
#define HH 30
#define EMBD 20
#define XD 80
#define G4 120

#define O_COV ((size_t)BB*VV)
#define O_H   (O_COV + (size_t)BB*SS)
#define O_C   (O_H + (size_t)BB*HH)
#define O_NA  (O_C + (size_t)BB*HH)
#define O_LOSS (O_NA + (size_t)BB*SS)

__device__ __forceinline__ float sigf(float x){ return 1.f/(1.f+__expf(-x)); }

__device__ __forceinline__ float bsum(float v, float* red, int tid){
  #pragma unroll
  for (int off=32; off; off>>=1) v += __shfl_xor(v, off);
  __syncthreads();
  if ((tid&63)==0) red[tid>>6]=v;
  __syncthreads();
  return red[0]+red[1]+red[2]+red[3];
}
__device__ __forceinline__ float bmax(float v, float* red, int tid){
  #pragma unroll
  for (int off=32; off; off>>=1) v = fmaxf(v, __shfl_xor(v, off));
  __syncthreads();
  if ((tid&63)==0) red[tid>>6]=v;
  __syncthreads();
  return fmaxf(fmaxf(red[0],red[1]),fmaxf(red[2],red[3]));
}

// One block per batch row: context einsum + LSTM + attention energy + softmax
// + coverage, all from a single LDS-staged copy of enc_out[b].
__global__ __launch_bounds__(256) void k_row(
  const float* __restrict__ coverage, const float* __restrict__ enc_out,
  const float* __restrict__ h0, const float* __restrict__ c0,
  const float* __restrict__ attn, const int* __restrict__ dec_input,
  const float* __restrict__ embedding,
  const float* __restrict__ w_ih, const float* __restrict__ w_hh,
  const float* __restrict__ b_ih, const float* __restrict__ b_hh,
  const float* __restrict__ attn_wh_w, const float* __restrict__ attn_wh_b,
  const float* __restrict__ attn_ws_w, const float* __restrict__ attn_ws_b,
  const float* __restrict__ attn_wc, const float* __restrict__ attn_v,
  const float* __restrict__ whv, const float* __restrict__ wsv, const float* __restrict__ wxv,
  float* __restrict__ out, float* __restrict__ pgen_ws, float* __restrict__ rowsum_ws,
  float* __restrict__ losspart_ws)
{
  const int b = blockIdx.x, tid = threadIdx.x;
  __shared__ float enc[SS*61];     // padded row stride 61 (gcd(61,32)=1 -> no bank conflicts)
  __shared__ float wT[EE*32];      // attn_wh_w transposed [e][h], row stride 32
  __shared__ float attn_s[SS], cov_s[SS];
  __shared__ float xls[XD], hls[HH], wsapp[HH], wc_s[HH], v_s[HH], gls[G4];
  __shared__ float ctxp[EE*4];
  __shared__ float red[4];

  // ---- stage enc_out[b] (200x60 f32) via float4; 60/4=15 float4 per s-row ----
  {
    const float4* ep = (const float4*)(enc_out + (size_t)b*(SS*EE));
    #pragma unroll
    for (int it=0; it<12; ++it){
      int i = tid + it*256;
      if (i < (SS*EE/4)) {
        float4 v = ep[i];
        int s = i/15, e4 = (i - s*15)*4;
        float* d = &enc[s*61+e4];
        d[0]=v.x; d[1]=v.y; d[2]=v.z; d[3]=v.w;
      }
    }
  }
  if (tid < SS) { attn_s[tid]=attn[(size_t)b*SS+tid]; cov_s[tid]=coverage[(size_t)b*SS+tid]; }
  for (int i=tid; i<EE*HH; i+=256){ int h=i/EE, e=i-h*EE; wT[e*32+h]=attn_wh_w[i]; }
  if (tid >= 256-HH) { int h = tid-(256-HH); wc_s[h]=attn_wc[h]; v_s[h]=attn_v[h]; }
  if (tid==0) rowsum_ws[b]=0.f;
  __syncthreads();

  // ---- context[e] = sum_s attn[s]*enc[s][e]  (240 threads: 4 partials x 60 e) ----
  if (tid < 240){
    int g = tid/60, e = tid - g*60;
    float acc=0.f;
    for (int s=g; s<SS; s+=4) acc += attn_s[s]*enc[s*61+e];
    ctxp[e*4+g]=acc;
  }
  __syncthreads();
  if (tid < EE) xls[tid]=ctxp[tid*4]+ctxp[tid*4+1]+ctxp[tid*4+2]+ctxp[tid*4+3];
  else if (tid < EE+EMBD){
    int k = tid-EE;
    int dix = dec_input[b];
    xls[tid] = embedding[(size_t)dix*EMBD+k];
  }
  __syncthreads();

  // ---- gates = x@w_ih.T + b_ih + h0@w_hh.T + b_hh ----
  if (tid < G4){
    float acc = b_ih[tid]+b_hh[tid];
    const float* wi = w_ih + tid*XD;
    #pragma unroll
    for (int k=0;k<XD;k++) acc += xls[k]*wi[k];
    const float* whh = w_hh + tid*HH;
    const float* h0b = h0 + (size_t)b*HH;
    #pragma unroll
    for (int k=0;k<HH;k++) acc += h0b[k]*whh[k];
    gls[tid]=acc;
  }
  __syncthreads();
  // ---- LSTM cell: i,f,g,o ----
  if (tid < HH){
    float c = sigf(gls[tid+HH])*c0[(size_t)b*HH+tid] + sigf(gls[tid])*tanhf(gls[tid+2*HH]);
    float h = sigf(gls[tid+3*HH])*tanhf(c);
    out[O_C+(size_t)b*HH+tid]=c;
    out[O_H+(size_t)b*HH+tid]=h;
    hls[tid]=h;
  }
  __syncthreads();
  // ---- ws_app (+ fold attn_wh_b) ----
  if (tid < HH){
    float acc = attn_ws_b[tid] + attn_wh_b[tid];
    const float* w = attn_ws_w + tid*HH;
    #pragma unroll
    for (int k=0;k<HH;k++) acc += hls[k]*w[k];
    wsapp[tid]=acc;
  }
  // ---- p_gen = sigmoid(ctx.wh + h.ws + emb.wx) ----
  float pv=0.f;
  if (tid<EE) pv = xls[tid]*whv[tid];
  else if (tid<EE+HH) pv = hls[tid-EE]*wsv[tid-EE];
  else if (tid<EE+HH+EMBD) pv = xls[EE+(tid-EE-HH)]*wxv[tid-EE-HH];
  float pg = sigf(bsum(pv,red,tid));   // bsum syncs also make wsapp visible
  if (tid==0) pgen_ws[b]=pg;
  __syncthreads();

  // ---- energy[s] = sum_h tanh(wh_app+ws_app+cov*wc)[h]*v[h] ----
  float en = -1e30f;
  if (tid < SS){
    float acc[HH];
    float cv = cov_s[tid];
    #pragma unroll
    for (int h=0;h<HH;h++) acc[h] = wsapp[h] + cv*wc_s[h];
    for (int e=0;e<EE;e++){
      float evv = enc[tid*61+e];
      #pragma unroll
      for (int h=0;h<HH;h++) acc[h] += evv*wT[e*32+h];
    }
    float e2=0.f;
    #pragma unroll
    for (int h=0;h<HH;h++) e2 += tanhf(acc[h])*v_s[h];
    en = e2;
  }
  // ---- softmax over S + coverage outputs ----
  float mx = bmax(en, red, tid);
  float ex = (tid<SS)? __expf(en-mx) : 0.f;
  float sm = bsum(ex, red, tid);
  float inv = 1.f/sm;
  float lossv = 0.f;
  if (tid<SS){
    float na = ex*inv;
    float cv = cov_s[tid];
    out[O_NA+(size_t)b*SS+tid]=na;
    out[O_COV+(size_t)b*SS+tid]=cv+na;
    lossv = fminf(na,cv);
  }
  float ls = bsum(lossv,red,tid);
  if (tid==0) losspart_ws[b]=ls;
}

// ---- vocab pass 1: rowsum[b] = sum_v exp(h.v_w[v]+v_b[v]) ----
__global__ __launch_bounds__(256) void k_sumexp(
  const float* __restrict__ v_w, const float* __restrict__ v_b,
  const float* __restrict__ hsrc, float* __restrict__ rowsum)
{
  __shared__ float wTs[HH*128];
  __shared__ float hTs[HH*32];
  __shared__ float vbs[128];
  const int tid=threadIdx.x;
  const int rbase=blockIdx.x*32, cbase=blockIdx.y*128;
  for (int i=tid;i<128*HH;i+=256){ int c=i/HH,k=i-c*HH; int v=cbase+c; wTs[k*128+c]=(v<VV)? v_w[(size_t)v*HH+k]:0.f; }
  for (int i=tid;i<32*HH;i+=256){ int r=i/HH,k=i-r*HH; hTs[k*32+r]=hsrc[(size_t)(rbase+r)*HH+k]; }
  if (tid<128){ int v=cbase+tid; vbs[tid]=(v<VV)? v_b[v] : -1e30f; } // -inf -> exp 0 for OOB cols
  __syncthreads();
  const int tc=tid&31, tr=tid>>5;
  float acc[4][4]={};
  #pragma unroll
  for (int k=0;k<HH;k++){
    const float4 hv=*(const float4*)&hTs[k*32+4*tr];
    const float w0=wTs[k*128+tc],w1=wTs[k*128+tc+32],w2=wTs[k*128+tc+64],w3=wTs[k*128+tc+96];
    acc[0][0]+=hv.x*w0; acc[0][1]+=hv.x*w1; acc[0][2]+=hv.x*w2; acc[0][3]+=hv.x*w3;
    acc[1][0]+=hv.y*w0; acc[1][1]+=hv.y*w1; acc[1][2]+=hv.y*w2; acc[1][3]+=hv.y*w3;
    acc[2][0]+=hv.z*w0; acc[2][1]+=hv.z*w1; acc[2][2]+=hv.z*w2; acc[2][3]+=hv.z*w3;
    acc[3][0]+=hv.w*w0; acc[3][1]+=hv.w*w1; acc[3][2]+=hv.w*w2; acc[3][3]+=hv.w*w3;
  }
  const float b0=vbs[tc],b1=vbs[tc+32],b2=vbs[tc+64],b3=vbs[tc+96];
  #pragma unroll
  for (int r=0;r<4;r++){
    float s = __expf(acc[r][0]+b0)+__expf(acc[r][1]+b1)+__expf(acc[r][2]+b2)+__expf(acc[r][3]+b3);
    #pragma unroll
    for (int off=16; off; off>>=1) s += __shfl_xor(s, off);
    if (tc==0) atomicAdd(&rowsum[rbase+4*tr+r], s);
  }
}

// ---- vocab pass 2: out[b,v] = exp(h.v_w[v] + v_b[v] + log(pgen)-log(rowsum)) ----
__global__ __launch_bounds__(256) void k_vocab(
  const float* __restrict__ v_w, const float* __restrict__ v_b,
  const float* __restrict__ hsrc, const float* __restrict__ pgen,
  const float* __restrict__ rowsum, float* __restrict__ out)
{
  __shared__ float wTs[HH*128];
  __shared__ float hTs[HH*32];
  __shared__ float vbs[128];
  __shared__ float offs[32];
  const int tid=threadIdx.x;
  const int rbase=blockIdx.x*32, cbase=blockIdx.y*128;
  for (int i=tid;i<128*HH;i+=256){ int c=i/HH,k=i-c*HH; int v=cbase+c; wTs[k*128+c]=(v<VV)? v_w[(size_t)v*HH+k]:0.f; }
  for (int i=tid;i<32*HH;i+=256){ int r=i/HH,k=i-r*HH; hTs[k*32+r]=hsrc[(size_t)(rbase+r)*HH+k]; }
  if (tid<128){ int v=cbase+tid; vbs[tid]=(v<VV)? v_b[v]:0.f; }
  else if (tid<160){ int r=tid-128; offs[r]=__logf(pgen[rbase+r])-__logf(rowsum[rbase+r]); }
  __syncthreads();
  const int tc=tid&31, tr=tid>>5;
  float acc[4][4]={};
  #pragma unroll
  for (int k=0;k<HH;k++){
    const float4 hv=*(const float4*)&hTs[k*32+4*tr];
    const float w0=wTs[k*128+tc],w1=wTs[k*128+tc+32],w2=wTs[k*128+tc+64],w3=wTs[k*128+tc+96];
    acc[0][0]+=hv.x*w0; acc[0][1]+=hv.x*w1; acc[0][2]+=hv.x*w2; acc[0][3]+=hv.x*w3;
    acc[1][0]+=hv.y*w0; acc[1][1]+=hv.y*w1; acc[1][2]+=hv.y*w2; acc[1][3]+=hv.y*w3;
    acc[2][0]+=hv.z*w0; acc[2][1]+=hv.z*w1; acc[2][2]+=hv.z*w2; acc[2][3]+=hv.z*w3;
    acc[3][0]+=hv.w*w0; acc[3][1]+=hv.w*w1; acc[3][2]+=hv.w*w2; acc[3][3]+=hv.w*w3;
  }
  const float b0=vbs[tc],b1=vbs[tc+32],b2=vbs[tc+64],b3=vbs[tc+96];
  const bool full = (cbase+128 <= VV);
  #pragma unroll
  for (int r=0;r<4;r++){
    const int row=rbase+4*tr+r;
    const float off=offs[4*tr+r];
    float o0=__expf(acc[r][0]+b0+off);
    float o1=__expf(acc[r][1]+b1+off);
    float o2=__expf(acc[r][2]+b2+off);
    float o3=__expf(acc[r][3]+b3+off);
    size_t base=(size_t)row*VV+cbase+tc;
    if (full){
      out[base]=o0; out[base+32]=o1; out[base+64]=o2; out[base+96]=o3;
    } else {
      if (cbase+tc<VV)    out[base]=o0;
      if (cbase+tc+32<VV) out[base+32]=o1;
      if (cbase+tc+64<VV) out[base+64]=o2;
      if (cbase+tc+96<VV) out[base+96]=o3;
    }
  }
}

// ---- scatter: numpy last-wins .at[rows, enc_inputs].set(new_attn), fused as += on p_gen*p_vocab ----
__global__ __launch_bounds__(256) void k_scatter(
  const int* __restrict__ enc_inputs, const float* __restrict__ pgen,
  const float* __restrict__ na, float* __restrict__ out)
{
  __shared__ int idx_s[SS];
  const int b=blockIdx.x, tid=threadIdx.x;
  if (tid<SS) idx_s[tid]=enc_inputs[(size_t)b*SS+tid];
  __syncthreads();
  if (tid<SS){
    int idx=idx_s[tid];
    bool last=true;
    for (int s2=tid+1;s2<SS;s2++) if (idx_s[s2]==idx){ last=false; break; }
    if (last){
      float add=(1.f-pgen[b])*na[(size_t)b*SS+tid];
      out[(size_t)b*VV+idx]+=add;
    }
  }
}

// ---- deterministic loss reduction ----
__global__ __launch_bounds__(256) void k_loss(const float* __restrict__ lp, float* __restrict__ dst){
  __shared__ float red[4];
  int tid=threadIdx.x;
  float s=0.f;
  for (int i=tid;i<BB;i+=256) s+=lp[i];
  #pragma unroll
  for (int off=32; off; off>>=1) s+=__shfl_xor(s,off);
  if ((tid&63)==0) red[tid>>6]=s;
  __syncthreads();
  if (tid==0) dst[0]=red[0]+red[1]+red[2]+red[3];
}

extern "C" void kernel_launch(void* const* d_in, const int* in_sizes, int n_in,
                              void* d_out, int out_size, void* d_ws, size_t ws_size,
                              hipStream_t stream)
{
  const float* coverage =(const float*)d_in[0];
  const float* enc_out  =(const float*)d_in[1];
  const float* h0       =(const float*)d_in[2];
  const float* c0       =(const float*)d_in[3];
  const float* attn     =(const float*)d_in[4];
  const int*   dec_input=(const int*)d_in[5];
  const int*   enc_inputs=(const int*)d_in[6];
  const float* embedding=(const float*)d_in[7];
  const float* w_ih     =(const float*)d_in[8];
  const float* w_hh     =(const float*)d_in[9];
  const float* b_ih     =(const float*)d_in[10];
  const float* b_hh     =(const float*)d_in[11];
  const float* attn_wh_w=(const float*)d_in[12];
  const float* attn_wh_b=(const float*)d_in[13];
  const float* attn_ws_w=(const float*)d_in[14];
  const float* attn_ws_b=(const float*)d_in[15];
  const float* attn_wc  =(const float*)d_in[16];
  const float* attn_v   =(const float*)d_in[17];
  const float* whv      =(const float*)d_in[18];
  const float* wsv      =(const float*)d_in[19];
  const float* wxv      =(const float*)d_in[20];
  const float* v_w      =(const float*)d_in[21];
  const float* v_b      =(const float*)d_in[22];
  float* out=(float*)d_out;
  float* wsf=(float*)d_ws;
  float* pgen=wsf; float* rowsum=wsf+BB; float* losspart=wsf+2*BB;

  k_row<<<BB,256,0,stream>>>(coverage,enc_out,h0,c0,attn,dec_input,embedding,
    w_ih,w_hh,b_ih,b_hh,attn_wh_w,attn_wh_b,attn_ws_w,attn_ws_b,attn_wc,attn_v,
    whv,wsv,wxv,out,pgen,rowsum,losspart);

  dim3 g2(BB/32, (VV+127)/128);
  k_sumexp<<<g2,256,0,stream>>>(v_w,v_b,out+O_H,rowsum);
  k_vocab <<<g2,256,0,stream>>>(v_w,v_b,out+O_H,pgen,rowsum,out);
  k_scatter<<<BB,256,0,stream>>>(enc_inputs,pgen,out+O_NA,out);
  k_loss<<<1,256,0,stream>>>(losspart,out+O_LOSS);
}

// Round 2
// 472.351 us; speedup vs baseline: 2.1217x; 2.1217x over previous
//
#include <hip/hip_runtime.h>

#define BB 2048
#define SS 200
#define VV 50257
#define EE 60
#define HH 30
#define EMBD 20
#define XD 80
#define G4 120
#define NCHUNK 50   /* ceil(50257/1024) */

#define O_COV ((size_t)BB*VV)
#define O_H   (O_COV + (size_t)BB*SS)
#define O_C   (O_H + (size_t)BB*HH)
#define O_NA  (O_C + (size_t)BB*HH)
#define O_LOSS (O_NA + (size_t)BB*SS)

typedef __attribute__((ext_vector_type(8))) short short8v;
typedef __attribute__((ext_vector_type(4))) float f32x4;

__device__ __forceinline__ float sigf(float x){ return 1.f/(1.f+__expf(-x)); }

__device__ __forceinline__ short f2bf(float f){
  union { __bf16 h; short s; } u; u.h = (__bf16)f; return u.s;
}

__device__ __forceinline__ float bsum(float v, float* red, int tid){
  #pragma unroll
  for (int off=32; off; off>>=1) v += __shfl_xor(v, off);
  __syncthreads();
  if ((tid&63)==0) red[tid>>6]=v;
  __syncthreads();
  return red[0]+red[1]+red[2]+red[3];
}
__device__ __forceinline__ float bmax(float v, float* red, int tid){
  #pragma unroll
  for (int off=32; off; off>>=1) v = fmaxf(v, __shfl_xor(v, off));
  __syncthreads();
  if ((tid&63)==0) red[tid>>6]=v;
  __syncthreads();
  return fmaxf(fmaxf(red[0],red[1]),fmaxf(red[2],red[3]));
}

// One block per batch row: context einsum + LSTM + attention energy + softmax
// + coverage, all from a single LDS-staged copy of enc_out[b].
__global__ __launch_bounds__(256) void k_row(
  const float* __restrict__ coverage, const float* __restrict__ enc_out,
  const float* __restrict__ h0, const float* __restrict__ c0,
  const float* __restrict__ attn, const int* __restrict__ dec_input,
  const float* __restrict__ embedding,
  const float* __restrict__ w_ih, const float* __restrict__ w_hh,
  const float* __restrict__ b_ih, const float* __restrict__ b_hh,
  const float* __restrict__ attn_wh_w, const float* __restrict__ attn_wh_b,
  const float* __restrict__ attn_ws_w, const float* __restrict__ attn_ws_b,
  const float* __restrict__ attn_wc, const float* __restrict__ attn_v,
  const float* __restrict__ whv, const float* __restrict__ wsv, const float* __restrict__ wxv,
  float* __restrict__ out, float* __restrict__ pgen_ws,
  float* __restrict__ losspart_ws)
{
  const int b = blockIdx.x, tid = threadIdx.x;
  __shared__ float enc[SS*61];     // padded row stride 61
  __shared__ float wT[EE*32];      // attn_wh_w transposed [e][h]
  __shared__ float attn_s[SS], cov_s[SS];
  __shared__ float xls[XD], hls[HH], wsapp[HH], wc_s[HH], v_s[HH], gls[G4];
  __shared__ float ctxp[EE*4];
  __shared__ float red[4];

  {
    const float4* ep = (const float4*)(enc_out + (size_t)b*(SS*EE));
    #pragma unroll
    for (int it=0; it<12; ++it){
      int i = tid + it*256;
      if (i < (SS*EE/4)) {
        float4 v = ep[i];
        int s = i/15, e4 = (i - s*15)*4;
        float* d = &enc[s*61+e4];
        d[0]=v.x; d[1]=v.y; d[2]=v.z; d[3]=v.w;
      }
    }
  }
  if (tid < SS) { attn_s[tid]=attn[(size_t)b*SS+tid]; cov_s[tid]=coverage[(size_t)b*SS+tid]; }
  for (int i=tid; i<EE*HH; i+=256){ int h=i/EE, e=i-h*EE; wT[e*32+h]=attn_wh_w[i]; }
  if (tid >= 256-HH) { int h = tid-(256-HH); wc_s[h]=attn_wc[h]; v_s[h]=attn_v[h]; }
  __syncthreads();

  if (tid < 240){
    int g = tid/60, e = tid - g*60;
    float acc=0.f;
    for (int s=g; s<SS; s+=4) acc += attn_s[s]*enc[s*61+e];
    ctxp[e*4+g]=acc;
  }
  __syncthreads();
  if (tid < EE) xls[tid]=ctxp[tid*4]+ctxp[tid*4+1]+ctxp[tid*4+2]+ctxp[tid*4+3];
  else if (tid < EE+EMBD){
    int k = tid-EE;
    int dix = dec_input[b];
    xls[tid] = embedding[(size_t)dix*EMBD+k];
  }
  __syncthreads();

  if (tid < G4){
    float acc = b_ih[tid]+b_hh[tid];
    const float* wi = w_ih + tid*XD;
    #pragma unroll
    for (int k=0;k<XD;k++) acc += xls[k]*wi[k];
    const float* whh = w_hh + tid*HH;
    const float* h0b = h0 + (size_t)b*HH;
    #pragma unroll
    for (int k=0;k<HH;k++) acc += h0b[k]*whh[k];
    gls[tid]=acc;
  }
  __syncthreads();
  if (tid < HH){
    float c = sigf(gls[tid+HH])*c0[(size_t)b*HH+tid] + sigf(gls[tid])*tanhf(gls[tid+2*HH]);
    float h = sigf(gls[tid+3*HH])*tanhf(c);
    out[O_C+(size_t)b*HH+tid]=c;
    out[O_H+(size_t)b*HH+tid]=h;
    hls[tid]=h;
  }
  __syncthreads();
  if (tid < HH){
    float acc = attn_ws_b[tid] + attn_wh_b[tid];
    const float* w = attn_ws_w + tid*HH;
    #pragma unroll
    for (int k=0;k<HH;k++) acc += hls[k]*w[k];
    wsapp[tid]=acc;
  }
  float pv=0.f;
  if (tid<EE) pv = xls[tid]*whv[tid];
  else if (tid<EE+HH) pv = hls[tid-EE]*wsv[tid-EE];
  else if (tid<EE+HH+EMBD) pv = xls[EE+(tid-EE-HH)]*wxv[tid-EE-HH];
  float pg = sigf(bsum(pv,red,tid));
  if (tid==0) pgen_ws[b]=pg;
  __syncthreads();

  float en = -1e30f;
  if (tid < SS){
    float acc[HH];
    float cv = cov_s[tid];
    #pragma unroll
    for (int h=0;h<HH;h++) acc[h] = wsapp[h] + cv*wc_s[h];
    for (int e=0;e<EE;e++){
      float evv = enc[tid*61+e];
      #pragma unroll
      for (int h=0;h<HH;h++) acc[h] += evv*wT[e*32+h];
    }
    float e2=0.f;
    #pragma unroll
    for (int h=0;h<HH;h++) e2 += tanhf(acc[h])*v_s[h];
    en = e2;
  }
  float mx = bmax(en, red, tid);
  float ex = (tid<SS)? __expf(en-mx) : 0.f;
  float sm = bsum(ex, red, tid);
  float inv = 1.f/sm;
  float lossv = 0.f;
  if (tid<SS){
    float na = ex*inv;
    float cv = cov_s[tid];
    out[O_NA+(size_t)b*SS+tid]=na;
    out[O_COV+(size_t)b*SS+tid]=cv+na;
    lossv = fminf(na,cv);
  }
  float ls = bsum(lossv,red,tid);
  if (tid==0) losspart_ws[b]=ls;
}

// ---- vocab pass 1 (MFMA): partial[chunk][row] = sum over chunk cols of exp(h.v_w[v]+v_b[v]) ----
// Block: 64 rows x 1024 cols. 4 waves, each wave 256 cols (16 tiles of 16).
__global__ __launch_bounds__(256) void k_vsum(
  const float* __restrict__ v_w, const float* __restrict__ v_b,
  const float* __restrict__ hsrc, float* __restrict__ partial)
{
  __shared__ float h_lds[64*36];   // stride 36: 16B-aligned float4 reads, 2-way banks (free)
  __shared__ float wred[4][64];
  const int tid = threadIdx.x;
  const int rbase = blockIdx.x*64;
  const int cbase = blockIdx.y*1024;
  for (int i=tid;i<64*HH;i+=256){ int r=i/HH,k=i-r*HH; h_lds[r*36+k]=hsrc[(size_t)(rbase+r)*HH+k]; }
  for (int i=tid;i<64*2;i+=256){ int r=i>>1; h_lds[r*36+HH+(i&1)]=0.f; }
  __syncthreads();

  const int w = tid>>6, l = tid&63;
  const int lc = l&15, lg = l>>4;

  union FragU { short8v v; short s[8]; };
  short8v Af[4];
  #pragma unroll
  for (int mt=0;mt<4;mt++){
    const float* hp = &h_lds[(mt*16+lc)*36 + lg*8];
    FragU fu;
    #pragma unroll
    for (int j=0;j<8;j++) fu.s[j] = f2bf(hp[j]);
    Af[mt]=fu.v;
  }

  float psum[4][4];
  #pragma unroll
  for (int mt=0;mt<4;mt++)
    #pragma unroll
    for (int r=0;r<4;r++) psum[mt][r]=0.f;

  const int wc0 = cbase + w*256;
  const int nk = (lg==3)?6:8;
  for (int t=0;t<16;t++){
    const int col = wc0 + t*16 + lc;
    const bool cv = (col < VV);
    FragU bu;
    if (cv){
      const float* wp = v_w + (size_t)col*HH + lg*8;
      #pragma unroll
      for (int j=0;j<8;j++) bu.s[j] = f2bf((j<nk)? wp[j] : 0.f);
    } else {
      #pragma unroll
      for (int j=0;j<8;j++) bu.s[j]=0;
    }
    const float vb = cv ? v_b[col] : 0.f;
    #pragma unroll
    for (int mt=0;mt<4;mt++){
      f32x4 z = {0.f,0.f,0.f,0.f};
      f32x4 lg4 = __builtin_amdgcn_mfma_f32_16x16x32_bf16(Af[mt], bu.v, z, 0,0,0);
      if (cv){
        #pragma unroll
        for (int r=0;r<4;r++) psum[mt][r] += __expf(lg4[r]+vb);
      }
    }
  }
  #pragma unroll
  for (int mt=0;mt<4;mt++){
    #pragma unroll
    for (int r=0;r<4;r++){
      float s = psum[mt][r];
      s += __shfl_xor(s,1); s += __shfl_xor(s,2); s += __shfl_xor(s,4); s += __shfl_xor(s,8);
      if (lc==0) wred[w][mt*16+lg*4+r]=s;
    }
  }
  __syncthreads();
  if (tid<64)
    partial[(size_t)blockIdx.y*BB + rbase + tid] =
      wred[0][tid]+wred[1][tid]+wred[2][tid]+wred[3][tid];
}

// ---- offs[row] = log(pgen[row]) - log(sum_c partial[c][row]) (deterministic) ----
__global__ __launch_bounds__(256) void k_off(
  const float* __restrict__ partial, const float* __restrict__ pgen,
  float* __restrict__ offs)
{
  const int row = blockIdx.x*256 + threadIdx.x;
  float s=0.f;
  #pragma unroll 5
  for (int c=0;c<NCHUNK;c++) s += partial[(size_t)c*BB + row];
  offs[row] = __logf(pgen[row]) - __logf(s);
}

// ---- vocab pass 2 (MFMA): out[b,v] = exp(h.v_w[v] + v_b[v] + offs[b]) ----
__global__ __launch_bounds__(256) void k_vwrite(
  const float* __restrict__ v_w, const float* __restrict__ v_b,
  const float* __restrict__ hsrc, const float* __restrict__ offs,
  float* __restrict__ out)
{
  __shared__ float h_lds[64*36];
  const int tid = threadIdx.x;
  const int rbase = blockIdx.x*64;
  const int cbase = blockIdx.y*1024;
  for (int i=tid;i<64*HH;i+=256){ int r=i/HH,k=i-r*HH; h_lds[r*36+k]=hsrc[(size_t)(rbase+r)*HH+k]; }
  for (int i=tid;i<64*2;i+=256){ int r=i>>1; h_lds[r*36+HH+(i&1)]=0.f; }
  __syncthreads();

  const int w = tid>>6, l = tid&63;
  const int lc = l&15, lg = l>>4;

  union FragU { short8v v; short s[8]; };
  short8v Af[4];
  float offv[4][4];
  #pragma unroll
  for (int mt=0;mt<4;mt++){
    const float* hp = &h_lds[(mt*16+lc)*36 + lg*8];
    FragU fu;
    #pragma unroll
    for (int j=0;j<8;j++) fu.s[j] = f2bf(hp[j]);
    Af[mt]=fu.v;
    #pragma unroll
    for (int r=0;r<4;r++) offv[mt][r] = offs[rbase + mt*16 + lg*4 + r];
  }

  const int wc0 = cbase + w*256;
  const int nk = (lg==3)?6:8;
  for (int t=0;t<16;t++){
    const int col = wc0 + t*16 + lc;
    const bool cv = (col < VV);
    FragU bu;
    if (cv){
      const float* wp = v_w + (size_t)col*HH + lg*8;
      #pragma unroll
      for (int j=0;j<8;j++) bu.s[j] = f2bf((j<nk)? wp[j] : 0.f);
    } else {
      #pragma unroll
      for (int j=0;j<8;j++) bu.s[j]=0;
    }
    const float vb = cv ? v_b[col] : 0.f;
    #pragma unroll
    for (int mt=0;mt<4;mt++){
      f32x4 z = {0.f,0.f,0.f,0.f};
      f32x4 lg4 = __builtin_amdgcn_mfma_f32_16x16x32_bf16(Af[mt], bu.v, z, 0,0,0);
      if (cv){
        float* op = out + (size_t)(rbase + mt*16 + lg*4)*VV + col;
        #pragma unroll
        for (int r=0;r<4;r++){
          op[0] = __expf(lg4[r]+vb+offv[mt][r]);
          op += VV;
        }
      }
    }
  }
}

// ---- scatter: numpy last-wins .at[rows, enc_inputs].set(new_attn), fused as += ----
__global__ __launch_bounds__(256) void k_scatter(
  const int* __restrict__ enc_inputs, const float* __restrict__ pgen,
  const float* __restrict__ na, float* __restrict__ out)
{
  __shared__ int idx_s[SS];
  const int b=blockIdx.x, tid=threadIdx.x;
  if (tid<SS) idx_s[tid]=enc_inputs[(size_t)b*SS+tid];
  __syncthreads();
  if (tid<SS){
    int idx=idx_s[tid];
    bool last=true;
    for (int s2=tid+1;s2<SS;s2++) if (idx_s[s2]==idx){ last=false; break; }
    if (last){
      float add=(1.f-pgen[b])*na[(size_t)b*SS+tid];
      out[(size_t)b*VV+idx]+=add;
    }
  }
}

__global__ __launch_bounds__(256) void k_loss(const float* __restrict__ lp, float* __restrict__ dst){
  __shared__ float red[4];
  int tid=threadIdx.x;
  float s=0.f;
  for (int i=tid;i<BB;i+=256) s+=lp[i];
  #pragma unroll
  for (int off=32; off; off>>=1) s+=__shfl_xor(s,off);
  if ((tid&63)==0) red[tid>>6]=s;
  __syncthreads();
  if (tid==0) dst[0]=red[0]+red[1]+red[2]+red[3];
}

extern "C" void kernel_launch(void* const* d_in, const int* in_sizes, int n_in,
                              void* d_out, int out_size, void* d_ws, size_t ws_size,
                              hipStream_t stream)
{
  const float* coverage =(const float*)d_in[0];
  const float* enc_out  =(const float*)d_in[1];
  const float* h0       =(const float*)d_in[2];
  const float* c0       =(const float*)d_in[3];
  const float* attn     =(const float*)d_in[4];
  const int*   dec_input=(const int*)d_in[5];
  const int*   enc_inputs=(const int*)d_in[6];
  const float* embedding=(const float*)d_in[7];
  const float* w_ih     =(const float*)d_in[8];
  const float* w_hh     =(const float*)d_in[9];
  const float* b_ih     =(const float*)d_in[10];
  const float* b_hh     =(const float*)d_in[11];
  const float* attn_wh_w=(const float*)d_in[12];
  const float* attn_wh_b=(const float*)d_in[13];
  const float* attn_ws_w=(const float*)d_in[14];
  const float* attn_ws_b=(const float*)d_in[15];
  const float* attn_wc  =(const float*)d_in[16];
  const float* attn_v   =(const float*)d_in[17];
  const float* whv      =(const float*)d_in[18];
  const float* wsv      =(const float*)d_in[19];
  const float* wxv      =(const float*)d_in[20];
  const float* v_w      =(const float*)d_in[21];
  const float* v_b      =(const float*)d_in[22];
  float* out=(float*)d_out;
  float* wsf=(float*)d_ws;
  float* pgen=wsf; float* losspart=wsf+BB; float* offs=wsf+2*BB; float* partial=wsf+3*BB;

  k_row<<<BB,256,0,stream>>>(coverage,enc_out,h0,c0,attn,dec_input,embedding,
    w_ih,w_hh,b_ih,b_hh,attn_wh_w,attn_wh_b,attn_ws_w,attn_ws_b,attn_wc,attn_v,
    whv,wsv,wxv,out,pgen,losspart);

  dim3 g2(BB/64, NCHUNK);
  k_vsum  <<<g2,256,0,stream>>>(v_w,v_b,out+O_H,partial);
  k_off   <<<BB/256,256,0,stream>>>(partial,pgen,offs);
  k_vwrite<<<g2,256,0,stream>>>(v_w,v_b,out+O_H,offs,out);
  k_scatter<<<BB,256,0,stream>>>(enc_inputs,pgen,out+O_NA,out);
  k_loss<<<1,256,0,stream>>>(losspart,out+O_LOSS);
}

// Round 3
// 471.223 us; speedup vs baseline: 2.1267x; 1.0024x over previous
//
#include <hip/hip_runtime.h>

#define BB 2048
#define SS 200
#define VV 50257
#define EE 60
#define HH 30
#define EMBD 20
#define XD 80
#define G4 120
#define NCHUNK 100      /* chunks of 512 cols */
#define VPAD 51200      /* NCHUNK*512 */

#define O_COV ((size_t)BB*VV)
#define O_H   (O_COV + (size_t)BB*SS)
#define O_C   (O_H + (size_t)BB*HH)
#define O_NA  (O_C + (size_t)BB*HH)
#define O_LOSS (O_NA + (size_t)BB*SS)

typedef __attribute__((ext_vector_type(8))) short short8v;
typedef __attribute__((ext_vector_type(4))) float f32x4;

__device__ __forceinline__ float sigf(float x){ return 1.f/(1.f+__expf(-x)); }

__device__ __forceinline__ short f2bf(float f){
  union { __bf16 h; short s; } u; u.h = (__bf16)f; return u.s;
}

__device__ __forceinline__ float bsum(float v, float* red, int tid){
  #pragma unroll
  for (int off=32; off; off>>=1) v += __shfl_xor(v, off);
  __syncthreads();
  if ((tid&63)==0) red[tid>>6]=v;
  __syncthreads();
  return red[0]+red[1]+red[2]+red[3];
}
__device__ __forceinline__ float bmax(float v, float* red, int tid){
  #pragma unroll
  for (int off=32; off; off>>=1) v = fmaxf(v, __shfl_xor(v, off));
  __syncthreads();
  if ((tid&63)==0) red[tid>>6]=v;
  __syncthreads();
  return fmaxf(fmaxf(red[0],red[1]),fmaxf(red[2],red[3]));
}

// ---- pack v_w -> bf16 [VPAD][32] (k zero-padded), v_b -> f32 [VPAD] (-1e30 pad) ----
__global__ __launch_bounds__(256) void k_pack(
  const float* __restrict__ v_w, const float* __restrict__ v_b,
  short* __restrict__ vw_bf, float* __restrict__ vb_pad)
{
  const int idx = blockIdx.x*256 + threadIdx.x;   // VPAD*4 quarter-rows
  const int col = idx>>2, q = idx&3;
  union { short8v v; short s[8]; } u;
  #pragma unroll
  for (int j=0;j<8;j++){
    int k = q*8+j;
    u.s[j] = (col<VV && k<HH) ? f2bf(v_w[(size_t)col*HH+k]) : (short)0;
  }
  ((short8v*)vw_bf)[idx] = u.v;
  if (q==0) vb_pad[col] = (col<VV) ? v_b[col] : -1e30f;
}

// One block per batch row: context einsum + LSTM + attention energy + softmax
// + coverage, from a single LDS-staged copy of enc_out[b]. Also emits packed h.
__global__ __launch_bounds__(256) void k_row(
  const float* __restrict__ coverage, const float* __restrict__ enc_out,
  const float* __restrict__ h0, const float* __restrict__ c0,
  const float* __restrict__ attn, const int* __restrict__ dec_input,
  const float* __restrict__ embedding,
  const float* __restrict__ w_ih, const float* __restrict__ w_hh,
  const float* __restrict__ b_ih, const float* __restrict__ b_hh,
  const float* __restrict__ attn_wh_w, const float* __restrict__ attn_wh_b,
  const float* __restrict__ attn_ws_w, const float* __restrict__ attn_ws_b,
  const float* __restrict__ attn_wc, const float* __restrict__ attn_v,
  const float* __restrict__ whv, const float* __restrict__ wsv, const float* __restrict__ wxv,
  float* __restrict__ out, float* __restrict__ pgen_ws,
  float* __restrict__ losspart_ws, short* __restrict__ h_bf)
{
  const int b = blockIdx.x, tid = threadIdx.x;
  __shared__ float enc[SS*61];
  __shared__ float wT[EE*32];
  __shared__ float attn_s[SS], cov_s[SS];
  __shared__ float xls[XD], hls[HH], wsapp[HH], wc_s[HH], v_s[HH], gls[G4];
  __shared__ float ctxp[EE*4];
  __shared__ float red[4];

  {
    const float4* ep = (const float4*)(enc_out + (size_t)b*(SS*EE));
    #pragma unroll
    for (int it=0; it<12; ++it){
      int i = tid + it*256;
      if (i < (SS*EE/4)) {
        float4 v = ep[i];
        int s = i/15, e4 = (i - s*15)*4;
        float* d = &enc[s*61+e4];
        d[0]=v.x; d[1]=v.y; d[2]=v.z; d[3]=v.w;
      }
    }
  }
  if (tid < SS) { attn_s[tid]=attn[(size_t)b*SS+tid]; cov_s[tid]=coverage[(size_t)b*SS+tid]; }
  for (int i=tid; i<EE*HH; i+=256){ int h=i/EE, e=i-h*EE; wT[e*32+h]=attn_wh_w[i]; }
  if (tid >= 256-HH) { int h = tid-(256-HH); wc_s[h]=attn_wc[h]; v_s[h]=attn_v[h]; }
  __syncthreads();

  if (tid < 240){
    int g = tid/60, e = tid - g*60;
    float acc=0.f;
    for (int s=g; s<SS; s+=4) acc += attn_s[s]*enc[s*61+e];
    ctxp[e*4+g]=acc;
  }
  __syncthreads();
  if (tid < EE) xls[tid]=ctxp[tid*4]+ctxp[tid*4+1]+ctxp[tid*4+2]+ctxp[tid*4+3];
  else if (tid < EE+EMBD){
    int k = tid-EE;
    int dix = dec_input[b];
    xls[tid] = embedding[(size_t)dix*EMBD+k];
  }
  __syncthreads();

  if (tid < G4){
    float acc = b_ih[tid]+b_hh[tid];
    const float* wi = w_ih + tid*XD;
    #pragma unroll
    for (int k=0;k<XD;k++) acc += xls[k]*wi[k];
    const float* whh = w_hh + tid*HH;
    const float* h0b = h0 + (size_t)b*HH;
    #pragma unroll
    for (int k=0;k<HH;k++) acc += h0b[k]*whh[k];
    gls[tid]=acc;
  }
  __syncthreads();
  if (tid < HH){
    float c = sigf(gls[tid+HH])*c0[(size_t)b*HH+tid] + sigf(gls[tid])*tanhf(gls[tid+2*HH]);
    float h = sigf(gls[tid+3*HH])*tanhf(c);
    out[O_C+(size_t)b*HH+tid]=c;
    out[O_H+(size_t)b*HH+tid]=h;
    hls[tid]=h;
  }
  __syncthreads();
  // packed bf16 h row [32] (k zero-padded)
  if (tid < 4){
    union { short8v v; short s[8]; } u;
    #pragma unroll
    for (int j=0;j<8;j++){ int k=tid*8+j; u.s[j] = (k<HH)? f2bf(hls[k]) : (short)0; }
    ((short8v*)(h_bf + (size_t)b*32))[tid] = u.v;
  }
  if (tid < HH){
    float acc = attn_ws_b[tid] + attn_wh_b[tid];
    const float* w = attn_ws_w + tid*HH;
    #pragma unroll
    for (int k=0;k<HH;k++) acc += hls[k]*w[k];
    wsapp[tid]=acc;
  }
  float pv=0.f;
  if (tid<EE) pv = xls[tid]*whv[tid];
  else if (tid<EE+HH) pv = hls[tid-EE]*wsv[tid-EE];
  else if (tid<EE+HH+EMBD) pv = xls[EE+(tid-EE-HH)]*wxv[tid-EE-HH];
  float pg = sigf(bsum(pv,red,tid));
  if (tid==0) pgen_ws[b]=pg;
  __syncthreads();

  float en = -1e30f;
  if (tid < SS){
    float acc[HH];
    float cv = cov_s[tid];
    #pragma unroll
    for (int h=0;h<HH;h++) acc[h] = wsapp[h] + cv*wc_s[h];
    for (int e=0;e<EE;e++){
      float evv = enc[tid*61+e];
      #pragma unroll
      for (int h=0;h<HH;h++) acc[h] += evv*wT[e*32+h];
    }
    float e2=0.f;
    #pragma unroll
    for (int h=0;h<HH;h++) e2 += tanhf(acc[h])*v_s[h];
    en = e2;
  }
  float mx = bmax(en, red, tid);
  float ex = (tid<SS)? __expf(en-mx) : 0.f;
  float sm = bsum(ex, red, tid);
  float inv = 1.f/sm;
  float lossv = 0.f;
  if (tid<SS){
    float na = ex*inv;
    float cv = cov_s[tid];
    out[O_NA+(size_t)b*SS+tid]=na;
    out[O_COV+(size_t)b*SS+tid]=cv+na;
    lossv = fminf(na,cv);
  }
  float ls = bsum(lossv,red,tid);
  if (tid==0) losspart_ws[b]=ls;
}

// ---- vocab pass 1 (MFMA): partial[chunk][row] = sum over 512 chunk cols of exp(h.v_w[v]+v_b[v]) ----
// Block: 64 rows x 512 cols, 4 waves, each wave 128 cols (8 tiles of 16).
__global__ __launch_bounds__(256) void k_vsum(
  const short* __restrict__ vw_bf, const float* __restrict__ vb_pad,
  const short* __restrict__ h_bf, float* __restrict__ partial)
{
  __shared__ short h_lds[64*32];
  __shared__ float wred[4][64];
  const int tid = threadIdx.x;
  const int rbase = blockIdx.x*64;
  const int cbase = blockIdx.y*512;
  ((uint4*)h_lds)[tid] = ((const uint4*)(h_bf + (size_t)rbase*32))[tid];
  __syncthreads();

  const int w = tid>>6, l = tid&63;
  const int lc = l&15, lg = l>>4;

  short8v Af[4];
  #pragma unroll
  for (int mt=0;mt<4;mt++)
    Af[mt] = *(const short8v*)&h_lds[(mt*16+lc)*32 + lg*8];

  float psum[4][4];
  #pragma unroll
  for (int mt=0;mt<4;mt++)
    #pragma unroll
    for (int r=0;r<4;r++) psum[mt][r]=0.f;

  const int wc0 = cbase + w*128;
  for (int t=0;t<8;t++){
    const int col = wc0 + t*16 + lc;
    short8v Bf = *(const short8v*)(vw_bf + (size_t)col*32 + lg*8);
    const float vb = vb_pad[col];
    #pragma unroll
    for (int mt=0;mt<4;mt++){
      f32x4 z = {0.f,0.f,0.f,0.f};
      f32x4 d = __builtin_amdgcn_mfma_f32_16x16x32_bf16(Af[mt], Bf, z, 0,0,0);
      #pragma unroll
      for (int r=0;r<4;r++) psum[mt][r] += __expf(d[r]+vb);
    }
  }
  #pragma unroll
  for (int mt=0;mt<4;mt++){
    #pragma unroll
    for (int r=0;r<4;r++){
      float s = psum[mt][r];
      s += __shfl_xor(s,1); s += __shfl_xor(s,2); s += __shfl_xor(s,4); s += __shfl_xor(s,8);
      if (lc==0) wred[w][mt*16+lg*4+r]=s;
    }
  }
  __syncthreads();
  if (tid<64)
    partial[(size_t)blockIdx.y*BB + rbase + tid] =
      wred[0][tid]+wred[1][tid]+wred[2][tid]+wred[3][tid];
}

// ---- offs[row] = log(pgen[row]) - log(sum_c partial[c][row]) (deterministic) ----
__global__ __launch_bounds__(256) void k_off(
  const float* __restrict__ partial, const float* __restrict__ pgen,
  float* __restrict__ offs)
{
  const int row = blockIdx.x*256 + threadIdx.x;
  float s=0.f;
  #pragma unroll 4
  for (int c=0;c<NCHUNK;c++) s += partial[(size_t)c*BB + row];
  offs[row] = __logf(pgen[row]) - __logf(s);
}

// ---- vocab pass 2 (MFMA): out[b,v] = exp(h.v_w[v] + v_b[v] + offs[b]) ----
__global__ __launch_bounds__(256) void k_vwrite(
  const short* __restrict__ vw_bf, const float* __restrict__ vb_pad,
  const short* __restrict__ h_bf, const float* __restrict__ offs,
  float* __restrict__ out)
{
  __shared__ short h_lds[64*32];
  const int tid = threadIdx.x;
  const int rbase = blockIdx.x*64;
  const int cbase = blockIdx.y*512;
  ((uint4*)h_lds)[tid] = ((const uint4*)(h_bf + (size_t)rbase*32))[tid];
  __syncthreads();

  const int w = tid>>6, l = tid&63;
  const int lc = l&15, lg = l>>4;

  short8v Af[4];
  float offv[4][4];
  #pragma unroll
  for (int mt=0;mt<4;mt++){
    Af[mt] = *(const short8v*)&h_lds[(mt*16+lc)*32 + lg*8];
    #pragma unroll
    for (int r=0;r<4;r++) offv[mt][r] = offs[rbase + mt*16 + lg*4 + r];
  }

  const int wc0 = cbase + w*128;
  for (int t=0;t<8;t++){
    const int col = wc0 + t*16 + lc;
    short8v Bf = *(const short8v*)(vw_bf + (size_t)col*32 + lg*8);
    const float vb = vb_pad[col];
    const bool cv = (col < VV);
    #pragma unroll
    for (int mt=0;mt<4;mt++){
      f32x4 z = {0.f,0.f,0.f,0.f};
      f32x4 d = __builtin_amdgcn_mfma_f32_16x16x32_bf16(Af[mt], Bf, z, 0,0,0);
      if (cv){
        float* op = out + (size_t)(rbase + mt*16 + lg*4)*VV + col;
        #pragma unroll
        for (int r=0;r<4;r++){
          op[0] = __expf(d[r]+vb+offv[mt][r]);
          op += VV;
        }
      }
    }
  }
}

// ---- scatter: numpy last-wins .at[rows, enc_inputs].set(new_attn), fused as += ----
__global__ __launch_bounds__(256) void k_scatter(
  const int* __restrict__ enc_inputs, const float* __restrict__ pgen,
  const float* __restrict__ na, float* __restrict__ out)
{
  __shared__ int idx_s[SS];
  const int b=blockIdx.x, tid=threadIdx.x;
  if (tid<SS) idx_s[tid]=enc_inputs[(size_t)b*SS+tid];
  __syncthreads();
  if (tid<SS){
    int idx=idx_s[tid];
    bool last=true;
    for (int s2=tid+1;s2<SS;s2++) if (idx_s[s2]==idx){ last=false; break; }
    if (last){
      float add=(1.f-pgen[b])*na[(size_t)b*SS+tid];
      out[(size_t)b*VV+idx]+=add;
    }
  }
}

__global__ __launch_bounds__(256) void k_loss(const float* __restrict__ lp, float* __restrict__ dst){
  __shared__ float red[4];
  int tid=threadIdx.x;
  float s=0.f;
  for (int i=tid;i<BB;i+=256) s+=lp[i];
  #pragma unroll
  for (int off=32; off; off>>=1) s+=__shfl_xor(s,off);
  if ((tid&63)==0) red[tid>>6]=s;
  __syncthreads();
  if (tid==0) dst[0]=red[0]+red[1]+red[2]+red[3];
}

extern "C" void kernel_launch(void* const* d_in, const int* in_sizes, int n_in,
                              void* d_out, int out_size, void* d_ws, size_t ws_size,
                              hipStream_t stream)
{
  const float* coverage =(const float*)d_in[0];
  const float* enc_out  =(const float*)d_in[1];
  const float* h0       =(const float*)d_in[2];
  const float* c0       =(const float*)d_in[3];
  const float* attn     =(const float*)d_in[4];
  const int*   dec_input=(const int*)d_in[5];
  const int*   enc_inputs=(const int*)d_in[6];
  const float* embedding=(const float*)d_in[7];
  const float* w_ih     =(const float*)d_in[8];
  const float* w_hh     =(const float*)d_in[9];
  const float* b_ih     =(const float*)d_in[10];
  const float* b_hh     =(const float*)d_in[11];
  const float* attn_wh_w=(const float*)d_in[12];
  const float* attn_wh_b=(const float*)d_in[13];
  const float* attn_ws_w=(const float*)d_in[14];
  const float* attn_ws_b=(const float*)d_in[15];
  const float* attn_wc  =(const float*)d_in[16];
  const float* attn_v   =(const float*)d_in[17];
  const float* whv      =(const float*)d_in[18];
  const float* wsv      =(const float*)d_in[19];
  const float* wxv      =(const float*)d_in[20];
  const float* v_w      =(const float*)d_in[21];
  const float* v_b      =(const float*)d_in[22];
  float* out=(float*)d_out;
  float* wsf=(float*)d_ws;
  float* pgen    = wsf;                 // 2048
  float* losspart= wsf + 2048;          // 2048
  float* offs    = wsf + 4096;          // 2048
  float* partial = wsf + 6144;          // NCHUNK*BB = 204800
  float* vb_pad  = wsf + 6144 + (size_t)NCHUNK*BB;          // 51200
  short* vw_bf   = (short*)(vb_pad + VPAD);                 // VPAD*32 shorts
  short* h_bf    = vw_bf + (size_t)VPAD*32;                 // BB*32 shorts

  k_pack<<<VPAD*4/256,256,0,stream>>>(v_w,v_b,vw_bf,vb_pad);

  k_row<<<BB,256,0,stream>>>(coverage,enc_out,h0,c0,attn,dec_input,embedding,
    w_ih,w_hh,b_ih,b_hh,attn_wh_w,attn_wh_b,attn_ws_w,attn_ws_b,attn_wc,attn_v,
    whv,wsv,wxv,out,pgen,losspart,h_bf);

  dim3 g2(BB/64, NCHUNK);
  k_vsum  <<<g2,256,0,stream>>>(vw_bf,vb_pad,h_bf,partial);
  k_off   <<<BB/256,256,0,stream>>>(partial,pgen,offs);
  k_vwrite<<<g2,256,0,stream>>>(vw_bf,vb_pad,h_bf,offs,out);
  k_scatter<<<BB,256,0,stream>>>(enc_inputs,pgen,out+O_NA,out);
  k_loss<<<1,256,0,stream>>>(losspart,out+O_LOSS);
}

// Round 5
// 360.289 us; speedup vs baseline: 2.7816x; 1.3079x over previous
//
#include <hip/hip_runtime.h>

#define BB 2048
#define SS 200
#define VV 50257
#define EE 60
#define HH 30
#define EMBD 20
#define XD 80
#define G4 120
#define NCHUNK 100      /* chunks of 512 cols (k_vsum) */
#define VPAD 51200
#define SROW 132        /* staging row stride (dwords) */

#define O_COV ((size_t)BB*VV)
#define O_H   (O_COV + (size_t)BB*SS)
#define O_C   (O_H + (size_t)BB*HH)
#define O_NA  (O_C + (size_t)BB*HH)
#define O_LOSS (O_NA + (size_t)BB*SS)

typedef __attribute__((ext_vector_type(8))) short short8v;
typedef __attribute__((ext_vector_type(4))) float f32x4;

__device__ __forceinline__ float sigf(float x){ return 1.f/(1.f+__expf(-x)); }

__device__ __forceinline__ short f2bf(float f){
  union { __bf16 h; short s; } u; u.h = (__bf16)f; return u.s;
}

__device__ __forceinline__ float bsum(float v, float* red, int tid){
  #pragma unroll
  for (int off=32; off; off>>=1) v += __shfl_xor(v, off);
  __syncthreads();
  if ((tid&63)==0) red[tid>>6]=v;
  __syncthreads();
  return red[0]+red[1]+red[2]+red[3];
}
__device__ __forceinline__ float bmax(float v, float* red, int tid){
  #pragma unroll
  for (int off=32; off; off>>=1) v = fmaxf(v, __shfl_xor(v, off));
  __syncthreads();
  if ((tid&63)==0) red[tid>>6]=v;
  __syncthreads();
  return fmaxf(fmaxf(red[0],red[1]),fmaxf(red[2],red[3]));
}

// ---- pack v_w -> bf16 [VPAD][32] (k zero-padded), v_b -> f32 [VPAD] (-1e30 pad) ----
__global__ __launch_bounds__(256) void k_pack(
  const float* __restrict__ v_w, const float* __restrict__ v_b,
  short* __restrict__ vw_bf, float* __restrict__ vb_pad)
{
  const int idx = blockIdx.x*256 + threadIdx.x;
  const int col = idx>>2, q = idx&3;
  union { short8v v; short s[8]; } u;
  #pragma unroll
  for (int j=0;j<8;j++){
    int k = q*8+j;
    u.s[j] = (col<VV && k<HH) ? f2bf(v_w[(size_t)col*HH+k]) : (short)0;
  }
  ((short8v*)vw_bf)[idx] = u.v;
  if (q==0) vb_pad[col] = (col<VV) ? v_b[col] : -1e30f;
}

// One block per batch row: context einsum + LSTM + attention energy + softmax
// + coverage, from a single LDS-staged copy of enc_out[b]. Also emits packed h.
__global__ __launch_bounds__(256) void k_row(
  const float* __restrict__ coverage, const float* __restrict__ enc_out,
  const float* __restrict__ h0, const float* __restrict__ c0,
  const float* __restrict__ attn, const int* __restrict__ dec_input,
  const float* __restrict__ embedding,
  const float* __restrict__ w_ih, const float* __restrict__ w_hh,
  const float* __restrict__ b_ih, const float* __restrict__ b_hh,
  const float* __restrict__ attn_wh_w, const float* __restrict__ attn_wh_b,
  const float* __restrict__ attn_ws_w, const float* __restrict__ attn_ws_b,
  const float* __restrict__ attn_wc, const float* __restrict__ attn_v,
  const float* __restrict__ whv, const float* __restrict__ wsv, const float* __restrict__ wxv,
  float* __restrict__ out, float* __restrict__ pgen_ws,
  float* __restrict__ losspart_ws, short* __restrict__ h_bf)
{
  const int b = blockIdx.x, tid = threadIdx.x;
  __shared__ float enc[SS*61];
  __shared__ float wT[EE*32];
  __shared__ float attn_s[SS], cov_s[SS];
  __shared__ float xls[XD], hls[HH], wsapp[HH], wc_s[HH], v_s[HH], gls[G4];
  __shared__ float ctxp[EE*4];
  __shared__ float red[4];

  {
    const float4* ep = (const float4*)(enc_out + (size_t)b*(SS*EE));
    #pragma unroll
    for (int it=0; it<12; ++it){
      int i = tid + it*256;
      if (i < (SS*EE/4)) {
        float4 v = ep[i];
        int s = i/15, e4 = (i - s*15)*4;
        float* d = &enc[s*61+e4];
        d[0]=v.x; d[1]=v.y; d[2]=v.z; d[3]=v.w;
      }
    }
  }
  if (tid < SS) { attn_s[tid]=attn[(size_t)b*SS+tid]; cov_s[tid]=coverage[(size_t)b*SS+tid]; }
  for (int i=tid; i<EE*HH; i+=256){ int h=i/EE, e=i-h*EE; wT[e*32+h]=attn_wh_w[i]; }
  if (tid >= 256-HH) { int h = tid-(256-HH); wc_s[h]=attn_wc[h]; v_s[h]=attn_v[h]; }
  __syncthreads();

  if (tid < 240){
    int g = tid/60, e = tid - g*60;
    float acc=0.f;
    for (int s=g; s<SS; s+=4) acc += attn_s[s]*enc[s*61+e];
    ctxp[e*4+g]=acc;
  }
  __syncthreads();
  if (tid < EE) xls[tid]=ctxp[tid*4]+ctxp[tid*4+1]+ctxp[tid*4+2]+ctxp[tid*4+3];
  else if (tid < EE+EMBD){
    int k = tid-EE;
    int dix = dec_input[b];
    xls[tid] = embedding[(size_t)dix*EMBD+k];
  }
  __syncthreads();

  if (tid < G4){
    float acc = b_ih[tid]+b_hh[tid];
    const float* wi = w_ih + tid*XD;
    #pragma unroll
    for (int k=0;k<XD;k++) acc += xls[k]*wi[k];
    const float* whh = w_hh + tid*HH;
    const float* h0b = h0 + (size_t)b*HH;
    #pragma unroll
    for (int k=0;k<HH;k++) acc += h0b[k]*whh[k];
    gls[tid]=acc;
  }
  __syncthreads();
  if (tid < HH){
    float c = sigf(gls[tid+HH])*c0[(size_t)b*HH+tid] + sigf(gls[tid])*tanhf(gls[tid+2*HH]);
    float h = sigf(gls[tid+3*HH])*tanhf(c);
    out[O_C+(size_t)b*HH+tid]=c;
    out[O_H+(size_t)b*HH+tid]=h;
    hls[tid]=h;
  }
  __syncthreads();
  if (tid < 4){
    union { short8v v; short s[8]; } u;
    #pragma unroll
    for (int j=0;j<8;j++){ int k=tid*8+j; u.s[j] = (k<HH)? f2bf(hls[k]) : (short)0; }
    ((short8v*)(h_bf + (size_t)b*32))[tid] = u.v;
  }
  if (tid < HH){
    float acc = attn_ws_b[tid] + attn_wh_b[tid];
    const float* w = attn_ws_w + tid*HH;
    #pragma unroll
    for (int k=0;k<HH;k++) acc += hls[k]*w[k];
    wsapp[tid]=acc;
  }
  float pv=0.f;
  if (tid<EE) pv = xls[tid]*whv[tid];
  else if (tid<EE+HH) pv = hls[tid-EE]*wsv[tid-EE];
  else if (tid<EE+HH+EMBD) pv = xls[EE+(tid-EE-HH)]*wxv[tid-EE-HH];
  float pg = sigf(bsum(pv,red,tid));
  if (tid==0) pgen_ws[b]=pg;
  __syncthreads();

  float en = -1e30f;
  if (tid < SS){
    float acc[HH];
    float cv = cov_s[tid];
    #pragma unroll
    for (int h=0;h<HH;h++) acc[h] = wsapp[h] + cv*wc_s[h];
    for (int e=0;e<EE;e++){
      float evv = enc[tid*61+e];
      #pragma unroll
      for (int h=0;h<HH;h++) acc[h] += evv*wT[e*32+h];
    }
    float e2=0.f;
    #pragma unroll
    for (int h=0;h<HH;h++) e2 += tanhf(acc[h])*v_s[h];
    en = e2;
  }
  float mx = bmax(en, red, tid);
  float ex = (tid<SS)? __expf(en-mx) : 0.f;
  float sm = bsum(ex, red, tid);
  float inv = 1.f/sm;
  float lossv = 0.f;
  if (tid<SS){
    float na = ex*inv;
    float cv = cov_s[tid];
    out[O_NA+(size_t)b*SS+tid]=na;
    out[O_COV+(size_t)b*SS+tid]=cv+na;
    lossv = fminf(na,cv);
  }
  float ls = bsum(lossv,red,tid);
  if (tid==0) losspart_ws[b]=ls;
}

// ---- vocab pass 1 (MFMA): partial[chunk][row] = sum over 512 chunk cols of exp(h.v_w[v]+v_b[v]) ----
__global__ __launch_bounds__(256) void k_vsum(
  const short* __restrict__ vw_bf, const float* __restrict__ vb_pad,
  const short* __restrict__ h_bf, float* __restrict__ partial)
{
  __shared__ short h_lds[64*32];
  __shared__ float wred[4][64];
  const int tid = threadIdx.x;
  const int rbase = blockIdx.x*64;
  const int cbase = blockIdx.y*512;
  ((uint4*)h_lds)[tid] = ((const uint4*)(h_bf + (size_t)rbase*32))[tid];
  __syncthreads();

  const int w = tid>>6, l = tid&63;
  const int lc = l&15, lg = l>>4;

  short8v Af[4];
  #pragma unroll
  for (int mt=0;mt<4;mt++)
    Af[mt] = *(const short8v*)&h_lds[(mt*16+lc)*32 + lg*8];

  float psum[4][4];
  #pragma unroll
  for (int mt=0;mt<4;mt++)
    #pragma unroll
    for (int r=0;r<4;r++) psum[mt][r]=0.f;

  const int wc0 = cbase + w*128;
  for (int t=0;t<8;t++){
    const int col = wc0 + t*16 + lc;
    short8v Bf = *(const short8v*)(vw_bf + (size_t)col*32 + lg*8);
    const float vb = vb_pad[col];
    #pragma unroll
    for (int mt=0;mt<4;mt++){
      f32x4 z = {0.f,0.f,0.f,0.f};
      f32x4 d = __builtin_amdgcn_mfma_f32_16x16x32_bf16(Af[mt], Bf, z, 0,0,0);
      #pragma unroll
      for (int r=0;r<4;r++) psum[mt][r] += __expf(d[r]+vb);
    }
  }
  #pragma unroll
  for (int mt=0;mt<4;mt++){
    #pragma unroll
    for (int r=0;r<4;r++){
      float s = psum[mt][r];
      s += __shfl_xor(s,1); s += __shfl_xor(s,2); s += __shfl_xor(s,4); s += __shfl_xor(s,8);
      if (lc==0) wred[w][mt*16+lg*4+r]=s;
    }
  }
  __syncthreads();
  if (tid<64)
    partial[(size_t)blockIdx.y*BB + rbase + tid] =
      wred[0][tid]+wred[1][tid]+wred[2][tid]+wred[3][tid];
}

// ---- offs[row] = log(pgen[row]) - log(sum_c partial[c][row]) ----
__global__ __launch_bounds__(256) void k_off(
  const float* __restrict__ partial, const float* __restrict__ pgen,
  float* __restrict__ offs)
{
  const int row = blockIdx.x*256 + threadIdx.x;
  float s=0.f;
  #pragma unroll 4
  for (int c=0;c<NCHUNK;c++) s += partial[(size_t)c*BB + row];
  offs[row] = __logf(pgen[row]) - __logf(s);
}

// ---- vocab pass 2 (MFMA): out[b,v] = exp(h.v_w[v] + v_b[v] + offs[b]) ----
// Block: 16 rows x 2048 cols, 4 waves. Each wave: 16x512 via 32 MFMA tiles in
// 4 chunks of 128 cols; exp()'d results staged in per-wave LDS, flushed as
// 64-lane contiguous dword rows (256B runs, non-temporal).
__global__ __launch_bounds__(256) void k_vwrite(
  const short* __restrict__ vw_bf, const float* __restrict__ vb_pad,
  const short* __restrict__ h_bf, const float* __restrict__ offs,
  float* __restrict__ out)
{
  __shared__ short h_lds[16*32];
  __shared__ float stage[4][16*SROW];
  const int tid = threadIdx.x;
  const int rbase = blockIdx.x*16;
  const int cbase = blockIdx.y*2048;
  if (tid < 64) ((uint4*)h_lds)[tid] = ((const uint4*)(h_bf + (size_t)rbase*32))[tid];  // 16*32 shorts = 64 uint4
  __syncthreads();

  const int w = tid>>6, l = tid&63;
  const int lc = l&15, lg = l>>4;

  short8v Af = *(const short8v*)&h_lds[lc*32 + lg*8];
  float offv[4];
  #pragma unroll
  for (int r=0;r<4;r++) offv[r] = offs[rbase + lg*4 + r];

  float* sw = stage[w];
  const int wc0 = cbase + w*512;

  for (int c=0;c<4;c++){
    const int c0 = wc0 + c*128;
    #pragma unroll
    for (int t=0;t<8;t++){
      const int col = c0 + t*16 + lc;
      short8v Bf = *(const short8v*)(vw_bf + (size_t)col*32 + lg*8);
      const float vb = vb_pad[col];
      f32x4 z = {0.f,0.f,0.f,0.f};
      f32x4 d = __builtin_amdgcn_mfma_f32_16x16x32_bf16(Af, Bf, z, 0,0,0);
      #pragma unroll
      for (int r=0;r<4;r++)
        sw[(lg*4+r)*SROW + t*16 + lc] = __expf(d[r]+vb+offv[r]);
    }
    // flush: same-wave LDS readback (DS ops in-order per wave; wave-private buffer)
    #pragma unroll 4
    for (int i=0;i<16;i++){
      float* op = out + (size_t)(rbase+i)*VV + c0;
      const float* sp = &sw[i*SROW];
      #pragma unroll
      for (int j=0;j<2;j++){
        const int ci = j*64 + l;
        if (c0 + ci < VV) __builtin_nontemporal_store(sp[ci], &op[ci]);
      }
    }
  }
}

// ---- scatter: numpy last-wins .at[rows, enc_inputs].set(new_attn), fused as += ----
__global__ __launch_bounds__(256) void k_scatter(
  const int* __restrict__ enc_inputs, const float* __restrict__ pgen,
  const float* __restrict__ na, float* __restrict__ out)
{
  __shared__ int idx_s[SS];
  const int b=blockIdx.x, tid=threadIdx.x;
  if (tid<SS) idx_s[tid]=enc_inputs[(size_t)b*SS+tid];
  __syncthreads();
  if (tid<SS){
    int idx=idx_s[tid];
    bool last=true;
    for (int s2=tid+1;s2<SS;s2++) if (idx_s[s2]==idx){ last=false; break; }
    if (last){
      float add=(1.f-pgen[b])*na[(size_t)b*SS+tid];
      out[(size_t)b*VV+idx]+=add;
    }
  }
}

__global__ __launch_bounds__(256) void k_loss(const float* __restrict__ lp, float* __restrict__ dst){
  __shared__ float red[4];
  int tid=threadIdx.x;
  float s=0.f;
  for (int i=tid;i<BB;i+=256) s+=lp[i];
  #pragma unroll
  for (int off=32; off; off>>=1) s+=__shfl_xor(s,off);
  if ((tid&63)==0) red[tid>>6]=s;
  __syncthreads();
  if (tid==0) dst[0]=red[0]+red[1]+red[2]+red[3];
}

extern "C" void kernel_launch(void* const* d_in, const int* in_sizes, int n_in,
                              void* d_out, int out_size, void* d_ws, size_t ws_size,
                              hipStream_t stream)
{
  const float* coverage =(const float*)d_in[0];
  const float* enc_out  =(const float*)d_in[1];
  const float* h0       =(const float*)d_in[2];
  const float* c0       =(const float*)d_in[3];
  const float* attn     =(const float*)d_in[4];
  const int*   dec_input=(const int*)d_in[5];
  const int*   enc_inputs=(const int*)d_in[6];
  const float* embedding=(const float*)d_in[7];
  const float* w_ih     =(const float*)d_in[8];
  const float* w_hh     =(const float*)d_in[9];
  const float* b_ih     =(const float*)d_in[10];
  const float* b_hh     =(const float*)d_in[11];
  const float* attn_wh_w=(const float*)d_in[12];
  const float* attn_wh_b=(const float*)d_in[13];
  const float* attn_ws_w=(const float*)d_in[14];
  const float* attn_ws_b=(const float*)d_in[15];
  const float* attn_wc  =(const float*)d_in[16];
  const float* attn_v   =(const float*)d_in[17];
  const float* whv      =(const float*)d_in[18];
  const float* wsv      =(const float*)d_in[19];
  const float* wxv      =(const float*)d_in[20];
  const float* v_w      =(const float*)d_in[21];
  const float* v_b      =(const float*)d_in[22];
  float* out=(float*)d_out;
  float* wsf=(float*)d_ws;
  float* pgen    = wsf;
  float* losspart= wsf + 2048;
  float* offs    = wsf + 4096;
  float* partial = wsf + 6144;
  float* vb_pad  = wsf + 6144 + (size_t)NCHUNK*BB;
  short* vw_bf   = (short*)(vb_pad + VPAD);
  short* h_bf    = vw_bf + (size_t)VPAD*32;

  k_pack<<<VPAD*4/256,256,0,stream>>>(v_w,v_b,vw_bf,vb_pad);

  k_row<<<BB,256,0,stream>>>(coverage,enc_out,h0,c0,attn,dec_input,embedding,
    w_ih,w_hh,b_ih,b_hh,attn_wh_w,attn_wh_b,attn_ws_w,attn_ws_b,attn_wc,attn_v,
    whv,wsv,wxv,out,pgen,losspart,h_bf);

  dim3 g2(BB/64, NCHUNK);
  k_vsum  <<<g2,256,0,stream>>>(vw_bf,vb_pad,h_bf,partial);
  k_off   <<<BB/256,256,0,stream>>>(partial,pgen,offs);
  dim3 gw(BB/16, VPAD/2048);
  k_vwrite<<<gw,256,0,stream>>>(vw_bf,vb_pad,h_bf,offs,out);
  k_scatter<<<BB,256,0,stream>>>(enc_inputs,pgen,out+O_NA,out);
  k_loss<<<1,256,0,stream>>>(losspart,out+O_LOSS);
}

// Round 6
// 332.585 us; speedup vs baseline: 3.0133x; 1.0833x over previous
//
#include <hip/hip_runtime.h>

#define BB 2048
#define SS 200
#define VV 50257
#define EE 60
#define HH 30
#define EMBD 20
#define XD 80
#define G4 120
#define NCHUNK 50       /* 1024-col groups (k_vsum) */
#define VPAD 51200
#define SROW 68         /* k_vwrite staging row stride (dwords), 64 used + 4 pad */

#define O_COV ((size_t)BB*VV)
#define O_H   (O_COV + (size_t)BB*SS)
#define O_C   (O_H + (size_t)BB*HH)
#define O_NA  (O_C + (size_t)BB*HH)
#define O_LOSS (O_NA + (size_t)BB*SS)

typedef __attribute__((ext_vector_type(8))) short short8v;
typedef __attribute__((ext_vector_type(4))) float f32x4;

__device__ __forceinline__ float sigf(float x){ return 1.f/(1.f+__expf(-x)); }

__device__ __forceinline__ short f2bf(float f){
  union { __bf16 h; short s; } u; u.h = (__bf16)f; return u.s;
}

__device__ __forceinline__ float bsum(float v, float* red, int tid){
  #pragma unroll
  for (int off=32; off; off>>=1) v += __shfl_xor(v, off);
  __syncthreads();
  if ((tid&63)==0) red[tid>>6]=v;
  __syncthreads();
  return red[0]+red[1]+red[2]+red[3];
}
__device__ __forceinline__ float bmax(float v, float* red, int tid){
  #pragma unroll
  for (int off=32; off; off>>=1) v = fmaxf(v, __shfl_xor(v, off));
  __syncthreads();
  if ((tid&63)==0) red[tid>>6]=v;
  __syncthreads();
  return fmaxf(fmaxf(red[0],red[1]),fmaxf(red[2],red[3]));
}

// ---- pack v_w -> bf16 [VPAD][32] (k zero-padded), v_b -> f32 [VPAD] (-1e30 pad) ----
__global__ __launch_bounds__(256) void k_pack(
  const float* __restrict__ v_w, const float* __restrict__ v_b,
  short* __restrict__ vw_bf, float* __restrict__ vb_pad)
{
  const int idx = blockIdx.x*256 + threadIdx.x;
  const int col = idx>>2, q = idx&3;
  union { short8v v; short s[8]; } u;
  #pragma unroll
  for (int j=0;j<8;j++){
    int k = q*8+j;
    u.s[j] = (col<VV && k<HH) ? f2bf(v_w[(size_t)col*HH+k]) : (short)0;
  }
  ((short8v*)vw_bf)[idx] = u.v;
  if (q==0) vb_pad[col] = (col<VV) ? v_b[col] : -1e30f;
}

// One block per batch row: context einsum + LSTM + attention energy + softmax
// + coverage, from a single LDS-staged copy of enc_out[b]. Also emits packed h.
__global__ __launch_bounds__(256) void k_row(
  const float* __restrict__ coverage, const float* __restrict__ enc_out,
  const float* __restrict__ h0, const float* __restrict__ c0,
  const float* __restrict__ attn, const int* __restrict__ dec_input,
  const float* __restrict__ embedding,
  const float* __restrict__ w_ih, const float* __restrict__ w_hh,
  const float* __restrict__ b_ih, const float* __restrict__ b_hh,
  const float* __restrict__ attn_wh_w, const float* __restrict__ attn_wh_b,
  const float* __restrict__ attn_ws_w, const float* __restrict__ attn_ws_b,
  const float* __restrict__ attn_wc, const float* __restrict__ attn_v,
  const float* __restrict__ whv, const float* __restrict__ wsv, const float* __restrict__ wxv,
  float* __restrict__ out, float* __restrict__ pgen_ws,
  float* __restrict__ losspart_ws, short* __restrict__ h_bf)
{
  const int b = blockIdx.x, tid = threadIdx.x;
  __shared__ float enc[SS*61];
  __shared__ float wT[EE*32];
  __shared__ float attn_s[SS], cov_s[SS];
  __shared__ float xls[XD], hls[HH], wsapp[HH], wc_s[HH], v_s[HH], gls[G4];
  __shared__ float ctxp[EE*4];
  __shared__ float red[4];

  {
    const float4* ep = (const float4*)(enc_out + (size_t)b*(SS*EE));
    #pragma unroll
    for (int it=0; it<12; ++it){
      int i = tid + it*256;
      if (i < (SS*EE/4)) {
        float4 v = ep[i];
        int s = i/15, e4 = (i - s*15)*4;
        float* d = &enc[s*61+e4];
        d[0]=v.x; d[1]=v.y; d[2]=v.z; d[3]=v.w;
      }
    }
  }
  if (tid < SS) { attn_s[tid]=attn[(size_t)b*SS+tid]; cov_s[tid]=coverage[(size_t)b*SS+tid]; }
  for (int i=tid; i<EE*HH; i+=256){ int h=i/EE, e=i-h*EE; wT[e*32+h]=attn_wh_w[i]; }
  if (tid >= 256-HH) { int h = tid-(256-HH); wc_s[h]=attn_wc[h]; v_s[h]=attn_v[h]; }
  __syncthreads();

  if (tid < 240){
    int g = tid/60, e = tid - g*60;
    float acc=0.f;
    for (int s=g; s<SS; s+=4) acc += attn_s[s]*enc[s*61+e];
    ctxp[e*4+g]=acc;
  }
  __syncthreads();
  if (tid < EE) xls[tid]=ctxp[tid*4]+ctxp[tid*4+1]+ctxp[tid*4+2]+ctxp[tid*4+3];
  else if (tid < EE+EMBD){
    int k = tid-EE;
    int dix = dec_input[b];
    xls[tid] = embedding[(size_t)dix*EMBD+k];
  }
  __syncthreads();

  if (tid < G4){
    float acc = b_ih[tid]+b_hh[tid];
    const float* wi = w_ih + tid*XD;
    #pragma unroll
    for (int k=0;k<XD;k++) acc += xls[k]*wi[k];
    const float* whh = w_hh + tid*HH;
    const float* h0b = h0 + (size_t)b*HH;
    #pragma unroll
    for (int k=0;k<HH;k++) acc += h0b[k]*whh[k];
    gls[tid]=acc;
  }
  __syncthreads();
  if (tid < HH){
    float c = sigf(gls[tid+HH])*c0[(size_t)b*HH+tid] + sigf(gls[tid])*tanhf(gls[tid+2*HH]);
    float h = sigf(gls[tid+3*HH])*tanhf(c);
    out[O_C+(size_t)b*HH+tid]=c;
    out[O_H+(size_t)b*HH+tid]=h;
    hls[tid]=h;
  }
  __syncthreads();
  if (tid < 4){
    union { short8v v; short s[8]; } u;
    #pragma unroll
    for (int j=0;j<8;j++){ int k=tid*8+j; u.s[j] = (k<HH)? f2bf(hls[k]) : (short)0; }
    ((short8v*)(h_bf + (size_t)b*32))[tid] = u.v;
  }
  if (tid < HH){
    float acc = attn_ws_b[tid] + attn_wh_b[tid];
    const float* w = attn_ws_w + tid*HH;
    #pragma unroll
    for (int k=0;k<HH;k++) acc += hls[k]*w[k];
    wsapp[tid]=acc;
  }
  float pv=0.f;
  if (tid<EE) pv = xls[tid]*whv[tid];
  else if (tid<EE+HH) pv = hls[tid-EE]*wsv[tid-EE];
  else if (tid<EE+HH+EMBD) pv = xls[EE+(tid-EE-HH)]*wxv[tid-EE-HH];
  float pg = sigf(bsum(pv,red,tid));
  if (tid==0) pgen_ws[b]=pg;
  __syncthreads();

  float en = -1e30f;
  if (tid < SS){
    float acc[HH];
    float cv = cov_s[tid];
    #pragma unroll
    for (int h=0;h<HH;h++) acc[h] = wsapp[h] + cv*wc_s[h];
    for (int e=0;e<EE;e++){
      float evv = enc[tid*61+e];
      #pragma unroll
      for (int h=0;h<HH;h++) acc[h] += evv*wT[e*32+h];
    }
    float e2=0.f;
    #pragma unroll
    for (int h=0;h<HH;h++) e2 += tanhf(acc[h])*v_s[h];
    en = e2;
  }
  float mx = bmax(en, red, tid);
  float ex = (tid<SS)? __expf(en-mx) : 0.f;
  float sm = bsum(ex, red, tid);
  float inv = 1.f/sm;
  float lossv = 0.f;
  if (tid<SS){
    float na = ex*inv;
    float cv = cov_s[tid];
    out[O_NA+(size_t)b*SS+tid]=na;
    out[O_COV+(size_t)b*SS+tid]=cv+na;
    lossv = fminf(na,cv);
  }
  float ls = bsum(lossv,red,tid);
  if (tid==0) losspart_ws[b]=ls;
}

// ---- vocab pass 1 (MFMA, LDS-free): wave = 16 rows x 1024 cols ----
// partial[cg][row] = sum over col-group of exp(h.v_w[v]+v_b[v])
__global__ __launch_bounds__(256) void k_vsum(
  const short* __restrict__ vw_bf, const float* __restrict__ vb_pad,
  const short* __restrict__ h_bf, float* __restrict__ partial)
{
  const int tid = threadIdx.x;
  const int w = tid>>6, l = tid&63;
  const int lc = l&15, lg = l>>4;
  const int task = blockIdx.x*4 + w;          // 0..6399
  const int rg = task & 127, cg = task >> 7;  // 128 row-groups x 50 col-groups
  const int rbase = rg*16, cbase = cg*1024;

  short8v Af = *(const short8v*)(h_bf + (size_t)(rbase+lc)*32 + lg*8);

  float psum[4] = {0.f,0.f,0.f,0.f};
  #pragma unroll 4
  for (int t=0;t<64;t++){
    const int col = cbase + t*16 + lc;
    short8v Bf = *(const short8v*)(vw_bf + (size_t)col*32 + lg*8);
    const float vb = vb_pad[col];
    f32x4 z = {0.f,0.f,0.f,0.f};
    f32x4 d = __builtin_amdgcn_mfma_f32_16x16x32_bf16(Af, Bf, z, 0,0,0);
    psum[0] += __expf(d[0]+vb);
    psum[1] += __expf(d[1]+vb);
    psum[2] += __expf(d[2]+vb);
    psum[3] += __expf(d[3]+vb);
  }
  #pragma unroll
  for (int r=0;r<4;r++){
    float s = psum[r];
    s += __shfl_xor(s,1); s += __shfl_xor(s,2); s += __shfl_xor(s,4); s += __shfl_xor(s,8);
    if (lc==0) partial[(size_t)cg*BB + rbase + lg*4 + r] = s;
  }
}

// ---- offs[row] = log(pgen[row]) - log(sum_c partial[c][row]) ----
__global__ __launch_bounds__(256) void k_off(
  const float* __restrict__ partial, const float* __restrict__ pgen,
  float* __restrict__ offs)
{
  const int row = blockIdx.x*256 + threadIdx.x;
  float s=0.f;
  #pragma unroll 5
  for (int c=0;c<NCHUNK;c++) s += partial[(size_t)c*BB + row];
  offs[row] = __logf(pgen[row]) - __logf(s);
}

// ---- vocab pass 2 (MFMA): out[b,v] = exp(h.v_w[v] + v_b[v] + offs[b]) ----
// Block: 16 rows x 2048 cols, 4 waves; wave = 16x512 in 8 chunks of 64 cols.
// exp results staged per-wave in LDS (18KB/block -> 8 blocks/CU), flushed as
// 64-lane contiguous dword rows (256B cached stores; L2 merges line fragments).
__global__ __launch_bounds__(256) void k_vwrite(
  const short* __restrict__ vw_bf, const float* __restrict__ vb_pad,
  const short* __restrict__ h_bf, const float* __restrict__ offs,
  float* __restrict__ out)
{
  __shared__ short h_lds[16*32];
  __shared__ float stage[4][16*SROW];
  const int tid = threadIdx.x;
  const int rbase = blockIdx.x*16;
  const int cbase = blockIdx.y*2048;
  if (tid < 64) ((uint4*)h_lds)[tid] = ((const uint4*)(h_bf + (size_t)rbase*32))[tid];
  __syncthreads();

  const int w = tid>>6, l = tid&63;
  const int lc = l&15, lg = l>>4;

  short8v Af = *(const short8v*)&h_lds[lc*32 + lg*8];
  float offv[4];
  #pragma unroll
  for (int r=0;r<4;r++) offv[r] = offs[rbase + lg*4 + r];

  float* sw = stage[w];
  const int wc0 = cbase + w*512;

  for (int c=0;c<8;c++){
    const int c0 = wc0 + c*64;
    #pragma unroll
    for (int t=0;t<4;t++){
      const int col = c0 + t*16 + lc;
      short8v Bf = *(const short8v*)(vw_bf + (size_t)col*32 + lg*8);
      const float vb = vb_pad[col];
      f32x4 z = {0.f,0.f,0.f,0.f};
      f32x4 d = __builtin_amdgcn_mfma_f32_16x16x32_bf16(Af, Bf, z, 0,0,0);
      #pragma unroll
      for (int r=0;r<4;r++)
        sw[(lg*4+r)*SROW + t*16 + lc] = __expf(d[r]+vb+offv[r]);
    }
    // flush: same-wave LDS readback (wave-private buffer, in-order DS ops)
    #pragma unroll 4
    for (int i=0;i<16;i++){
      if (c0 + l < VV)
        out[(size_t)(rbase+i)*VV + c0 + l] = sw[i*SROW + l];
    }
  }
}

// ---- scatter: numpy last-wins .at[rows, enc_inputs].set(new_attn), fused as += ----
__global__ __launch_bounds__(256) void k_scatter(
  const int* __restrict__ enc_inputs, const float* __restrict__ pgen,
  const float* __restrict__ na, float* __restrict__ out)
{
  __shared__ int idx_s[SS];
  const int b=blockIdx.x, tid=threadIdx.x;
  if (tid<SS) idx_s[tid]=enc_inputs[(size_t)b*SS+tid];
  __syncthreads();
  if (tid<SS){
    int idx=idx_s[tid];
    bool last=true;
    for (int s2=tid+1;s2<SS;s2++) if (idx_s[s2]==idx){ last=false; break; }
    if (last){
      float add=(1.f-pgen[b])*na[(size_t)b*SS+tid];
      out[(size_t)b*VV+idx]+=add;
    }
  }
}

__global__ __launch_bounds__(256) void k_loss(const float* __restrict__ lp, float* __restrict__ dst){
  __shared__ float red[4];
  int tid=threadIdx.x;
  float s=0.f;
  for (int i=tid;i<BB;i+=256) s+=lp[i];
  #pragma unroll
  for (int off=32; off; off>>=1) s+=__shfl_xor(s,off);
  if ((tid&63)==0) red[tid>>6]=s;
  __syncthreads();
  if (tid==0) dst[0]=red[0]+red[1]+red[2]+red[3];
}

extern "C" void kernel_launch(void* const* d_in, const int* in_sizes, int n_in,
                              void* d_out, int out_size, void* d_ws, size_t ws_size,
                              hipStream_t stream)
{
  const float* coverage =(const float*)d_in[0];
  const float* enc_out  =(const float*)d_in[1];
  const float* h0       =(const float*)d_in[2];
  const float* c0       =(const float*)d_in[3];
  const float* attn     =(const float*)d_in[4];
  const int*   dec_input=(const int*)d_in[5];
  const int*   enc_inputs=(const int*)d_in[6];
  const float* embedding=(const float*)d_in[7];
  const float* w_ih     =(const float*)d_in[8];
  const float* w_hh     =(const float*)d_in[9];
  const float* b_ih     =(const float*)d_in[10];
  const float* b_hh     =(const float*)d_in[11];
  const float* attn_wh_w=(const float*)d_in[12];
  const float* attn_wh_b=(const float*)d_in[13];
  const float* attn_ws_w=(const float*)d_in[14];
  const float* attn_ws_b=(const float*)d_in[15];
  const float* attn_wc  =(const float*)d_in[16];
  const float* attn_v   =(const float*)d_in[17];
  const float* whv      =(const float*)d_in[18];
  const float* wsv      =(const float*)d_in[19];
  const float* wxv      =(const float*)d_in[20];
  const float* v_w      =(const float*)d_in[21];
  const float* v_b      =(const float*)d_in[22];
  float* out=(float*)d_out;
  float* wsf=(float*)d_ws;
  float* pgen    = wsf;
  float* losspart= wsf + 2048;
  float* offs    = wsf + 4096;
  float* partial = wsf + 6144;
  float* vb_pad  = wsf + 6144 + (size_t)NCHUNK*BB;
  short* vw_bf   = (short*)(vb_pad + VPAD);
  short* h_bf    = vw_bf + (size_t)VPAD*32;

  k_pack<<<VPAD*4/256,256,0,stream>>>(v_w,v_b,vw_bf,vb_pad);

  k_row<<<BB,256,0,stream>>>(coverage,enc_out,h0,c0,attn,dec_input,embedding,
    w_ih,w_hh,b_ih,b_hh,attn_wh_w,attn_wh_b,attn_ws_w,attn_ws_b,attn_wc,attn_v,
    whv,wsv,wxv,out,pgen,losspart,h_bf);

  k_vsum  <<<1600,256,0,stream>>>(vw_bf,vb_pad,h_bf,partial);
  k_off   <<<BB/256,256,0,stream>>>(partial,pgen,offs);
  dim3 gw(BB/16, VPAD/2048);
  k_vwrite<<<gw,256,0,stream>>>(vw_bf,vb_pad,h_bf,offs,out);
  k_scatter<<<BB,256,0,stream>>>(enc_inputs,pgen,out+O_NA,out);
  k_loss<<<1,256,0,stream>>>(losspart,out+O_LOSS);
}